// Round 1
// baseline (92.886 us; speedup 1.0000x reference)
//
#include <hip/hip_runtime.h>
#include <hip/hip_bf16.h>

// Problem constants (ODST forward):
//   x    [B=1024, I=256]  fsl [I=256,N=512,D=6]  th/lt [N=512,D=6]
//   resp [N=512, U=16, C=64]   out [B=1024, U=16]
#define B_SZ 1024
#define I_SZ 256
#define N_SZ 512
#define D_SZ 6
#define U_SZ 16
#define C_SZ 64
#define NSPLIT 64            // 8 n (48 k' rows) per fused block

typedef __bf16 bf16_t;
typedef bf16_t bf16x8 __attribute__((ext_vector_type(8)));
typedef float  f32x4  __attribute__((ext_vector_type(4)));

// Fragment-order ("packed") operand layouts (verified R9/R10). A 16x16x32 MFMA
// operand frag is 64 lanes x 16 B; packed offset = (frag_linear*64 + lane)*16 B
// so a wave's frag load is one contiguous 1-KB burst (R7's direct loads put
// each lane on its own row -> 64 lines/instruction -> TA serialization).
//   selF:  frag (g=k'/16, kk) lane(lm,q) = sel[i=kk*32+q*8+jj][k'=g*16+lm]
//   xbF:   frag (gb=b/16, kk) lane(lm,q) = x[b=gb*16+lm][i=kk*32+q*8+jj]
//   respF: frag (n, chunk)    lane(lm,q) = resp[n][u=lm][c=chunk*32+q*8+jj]
//   sb[kp] = (scale, bias) = (exp(-lt), -th*exp(-lt))  — tl = fv*scale + bias
//
// R11 structural change: fused_k's 1M scalar atomicAdds into the 64KB out
// (64 blocks RMW-ing each line from different XCDs -> coherence-point
// serialization) are replaced by contention-free f32x4 partial stores into
// part[ns][btile][wave][lane][4] (4 MB, each slot written exactly once) +
// a 64-block reduce_k that sums the 64 ns slices and writes out directly.
// prep_pack's out-zero branch is dropped (reduce overwrites all of out).

// ---------------------------------------------------------------------------
// prep_pack: one dispatch, four block ranges (branch is block-uniform).
//   bid [0,512)   : sparsemax (16i x 16n tile, coalesced fsl) -> selF
//   bid [512,576) : x 16-row tile -> LDS -> xbF
//   bid [576,704) : resp 4-n tile -> LDS -> respF
//   bid [704,716) : sb = (exp(-lt), -th*exp(-lt))
// ---------------------------------------------------------------------------
__global__ __launch_bounds__(256) void prep_pack(
    const float* __restrict__ fsl, const float* __restrict__ x,
    const float* __restrict__ resp, const float* __restrict__ th,
    const float* __restrict__ lt,
    bf16_t* __restrict__ selF, bf16_t* __restrict__ xbF,
    bf16_t* __restrict__ respF, float2* __restrict__ sb) {
  __shared__ float smem[4160];   // 16640 B, reused per branch
  const int bid = blockIdx.x, t = threadIdx.x;

  if (bid < 512) {
    // ---- sparsemax: nb = n-tile (16 n), ib = i-tile (16 i)
    float (*sT)[17] = (float(*)[17])smem;          // [96][17]
    const int nb = bid & 31, ib = bid >> 5;
    const int i_loc = t >> 4, n_loc = t & 15;
    const int n0 = nb * 16, i0 = ib * 16;

    const float* z = fsl + ((size_t)(i0 + i_loc) * N_SZ + (n0 + n_loc)) * D_SZ;
    float v[D_SZ], s[D_SZ];
#pragma unroll
    for (int d = 0; d < D_SZ; ++d) { v[d] = z[d]; s[d] = v[d]; }
#define CSWAP(a, b) { float hi = fmaxf(s[a], s[b]); float lo = fminf(s[a], s[b]); s[a] = hi; s[b] = lo; }
#pragma unroll
    for (int r = 0; r < 3; ++r) {
      CSWAP(0, 1) CSWAP(2, 3) CSWAP(4, 5)
      CSWAP(1, 2) CSWAP(3, 4)
    }
#undef CSWAP
    float cs[D_SZ];
    cs[0] = s[0];
#pragma unroll
    for (int j = 1; j < D_SZ; ++j) cs[j] = cs[j - 1] + s[j];
    int kz = 0;
#pragma unroll
    for (int j = 0; j < D_SZ; ++j)
      kz += (1.0f + (float)(j + 1) * s[j] > cs[j]) ? 1 : 0;
    const float tau = (cs[kz - 1] - 1.0f) / (float)kz;
#pragma unroll
    for (int d = 0; d < D_SZ; ++d)
      sT[n_loc * 6 + d][i_loc] = fmaxf(v[d] - tau, 0.0f);
    __syncthreads();

    if (t < 192) {
      const int r = t >> 1, h = t & 1;             // r: 96 k' rows, h: i half
      const int g  = 6 * nb + (r >> 4), lm = r & 15;
      const int kk = ib >> 1, q = (ib & 1) * 2 + h;
      bf16x8 o;
#pragma unroll
      for (int jj = 0; jj < 8; ++jj) o[jj] = (bf16_t)sT[r][h * 8 + jj];
      *(bf16x8*)(selF + ((size_t)(g * 8 + kk) * 64 + q * 16 + lm) * 8) = o;
    }
  } else if (bid < 576) {
    // ---- x pack: 16 b rows -> 8 frags x 64 lanes = 512 writes (2 rounds)
    float (*xs)[257] = (float(*)[257])smem;        // [16][257]
    const int gb = bid - 512;
#pragma unroll
    for (int c = 0; c < 4; ++c) {
      const int e = c * 256 + t;                   // float4 index, 64 per row
      const int row = e >> 6, col = (e & 63) * 4;
      const float4 v = *(const float4*)(x + (size_t)(gb * 16 + row) * I_SZ + col);
      xs[row][col] = v.x; xs[row][col + 1] = v.y;
      xs[row][col + 2] = v.z; xs[row][col + 3] = v.w;
    }
    __syncthreads();
#pragma unroll
    for (int h = 0; h < 2; ++h) {
      const int fid = h * 256 + t;                 // 0..511
      const int kk = fid >> 6, lane = fid & 63;
      const int lm = lane & 15, q = lane >> 4;
      bf16x8 o;
#pragma unroll
      for (int jj = 0; jj < 8; ++jj) o[jj] = (bf16_t)xs[lm][kk * 32 + q * 8 + jj];
      *(bf16x8*)(xbF + ((size_t)(gb * 8 + kk) * 64 + lane) * 8) = o;
    }
  } else if (bid < 704) {
    // ---- resp pack: 4 n rows -> 4n x 2chunk x 64lane = 512 writes (2 rounds)
    float (*rs)[16][65] = (float(*)[16][65])smem;  // [4][16][65]
    const int n0 = (bid - 576) * 4;
#pragma unroll
    for (int c = 0; c < 4; ++c) {
      const int e = c * 256 + t;                   // float4 index, 256 per n
      const int n_loc = e >> 8, idx = (e & 255) * 4;
      const int u = idx >> 6, cc = idx & 63;
      const float4 v = *(const float4*)(resp + (size_t)(n0 + n_loc) * 1024 + idx);
      rs[n_loc][u][cc] = v.x; rs[n_loc][u][cc + 1] = v.y;
      rs[n_loc][u][cc + 2] = v.z; rs[n_loc][u][cc + 3] = v.w;
    }
    __syncthreads();
#pragma unroll
    for (int h = 0; h < 2; ++h) {
      const int fid = h * 256 + t;                 // 0..511
      const int n_loc = fid >> 7, chunk = (fid >> 6) & 1, lane = fid & 63;
      const int lm = lane & 15, q = lane >> 4;
      bf16x8 o;
#pragma unroll
      for (int jj = 0; jj < 8; ++jj)
        o[jj] = (bf16_t)rs[n_loc][lm][chunk * 32 + q * 8 + jj];
      *(bf16x8*)(respF + ((size_t)((n0 + n_loc) * 2 + chunk) * 64 + lane) * 8) = o;
    }
  } else {
    // ---- sb: tl = fv*scale + bias with scale=exp(-lt), bias=-th*scale
    const int i = (bid - 704) * 256 + t;           // < 3072
    const float sc = __expf(-lt[i]);
    sb[i] = make_float2(sc, -th[i] * sc);
  }
}

// ---------------------------------------------------------------------------
// fused_k: block (btile, ns) owns b in [btile*64,+64), n in [ns*8,+8).
//  Phase A (all 4 waves): wave w = b-subtile, 3 k'-group accumulators;
//    24 MFMA + 32 coalesced 1-KB frag loads. Epilogue: single fma with
//    precomputed sb. respF frags for n=0..3 are register-prefetched BEFORE
//    the barrier so Phase B starts compute-ready; n=4..7 loads hide behind
//    n=0..3's VALU work.
//  Phase B: bins from LDS fv, per-lane leaf-weight A-frags (c-bits: jj=0-2
//    frag elem, q=3-4 lane quad, chunk=5), 2 MFMA per n.
//  Epilogue (R11): ONE coalesced f32x4 store per lane into
//    part[ns][btile][wave][lane][4] — no atomics, no cross-block contention.
// ---------------------------------------------------------------------------
__global__ __launch_bounds__(256, 4) void fused_k(
    const bf16_t* __restrict__ selF,  // packed [192][8][64][8]
    const bf16_t* __restrict__ xbF,   // packed [64][8][64][8]
    const float2* __restrict__ sb,    // [3072] (scale, bias)
    const bf16_t* __restrict__ respF, // packed [512][2][64][8]
    float* __restrict__ part) {       // [64 ns][16 btile][4 wave][64 lane][4]
  __shared__ float fv[48][68];        // [k'_loc][b_loc], pad 68
  const int t = threadIdx.x;
  const int lane = t & 63, wave = t >> 6;
  const int lm = lane & 15, q = lane >> 4;
  const int btile = blockIdx.x & 15, ns = blockIdx.x >> 4;

  // ---- Phase A: GEMM 48 k' x 64 b; wave w = b-subtile w
  bf16x8 rpre[8];   // respF frags for n = ns*8 + 0..3 (both chunks)
  {
    f32x4 acc[3];
#pragma unroll
    for (int kg = 0; kg < 3; ++kg) acc[kg] = (f32x4){0.f, 0.f, 0.f, 0.f};
    const bf16_t* aF = selF + ((size_t)(ns * 3) * 8 * 64 + lane) * 8;
    const bf16_t* bF = xbF + ((size_t)(btile * 4 + wave) * 8 * 64 + lane) * 8;
#pragma unroll
    for (int kk = 0; kk < 8; ++kk) {
      const bf16x8 bv = *(const bf16x8*)(bF + (size_t)kk * 64 * 8);
#pragma unroll
      for (int kg = 0; kg < 3; ++kg) {
        const bf16x8 a = *(const bf16x8*)(aF + (size_t)(kg * 8 + kk) * 64 * 8);
        acc[kg] = __builtin_amdgcn_mfma_f32_16x16x32_bf16(a, bv, acc[kg], 0, 0, 0);
      }
    }

    // prefetch Phase B's first-half respF frags (issue before the barrier)
    const bf16_t* rF0 = respF + ((size_t)(ns * 8) * 2 * 64 + lane) * 8;
#pragma unroll
    for (int p = 0; p < 8; ++p)
      rpre[p] = *(const bf16x8*)(rF0 + (size_t)p * 64 * 8);

    // C/D: row(k'_loc) = kg*16 + q*4 + r, col(b_loc) = wave*16 + lm
#pragma unroll
    for (int kg = 0; kg < 3; ++kg)
#pragma unroll
      for (int r = 0; r < 4; ++r) {
        const float2 sv = sb[ns * 48 + kg * 16 + q * 4 + r];
        fv[kg * 16 + q * 4 + r][wave * 16 + lm] = fmaf(acc[kg][r], sv.x, sv.y);
      }
  }
  __syncthreads();

  // ---- Phase B: tree eval; wave handles b_loc in [wave*16, +16)
  f32x4 acc = (f32x4){0.f, 0.f, 0.f, 0.f};
  const int bloc = wave * 16 + lm;

#pragma unroll
  for (int j = 0; j < 8; ++j) {
    const int n = ns * 8 + j;
    bf16x8 bv0, bv1;
    if (j < 4) {
      bv0 = rpre[j * 2]; bv1 = rpre[j * 2 + 1];
    } else {
      const bf16_t* rF = respF + ((size_t)n * 2 * 64 + lane) * 8;
      bv0 = *(const bf16x8*)(rF);
      bv1 = *(const bf16x8*)(rF + 64 * 8);
    }

    float b0v[D_SZ], b1v[D_SZ];
#pragma unroll
    for (int d = 0; d < D_SZ; ++d) {
      const float tl = fv[j * 6 + d][bloc];
      b1v[d] = fminf(fmaxf(0.5f * tl + 0.5f, 0.0f), 1.0f);  // bit = 0
      b0v[d] = fminf(fmaxf(0.5f - 0.5f * tl, 0.0f), 1.0f);  // bit = 1
    }
    float p2[2], p4[4], p8[8];
    p2[0] = b1v[0]; p2[1] = b0v[0];
#pragma unroll
    for (int i = 0; i < 4; ++i) p4[i] = p2[i & 1] * ((i & 2) ? b0v[1] : b1v[1]);
#pragma unroll
    for (int i = 0; i < 8; ++i) p8[i] = p4[i & 3] * ((i & 4) ? b0v[2] : b1v[2]);
    const float f3 = (q & 1) ? b0v[3] : b1v[3];
    const float f4 = (q & 2) ? b0v[4] : b1v[4];
    const float fq = f3 * f4;
    const float g0 = fq * b1v[5];   // chunk 0: bit5 = 0
    const float g1 = fq * b0v[5];   // chunk 1: bit5 = 1

    bf16x8 a0, a1;
#pragma unroll
    for (int jj = 0; jj < 8; ++jj) {
      a0[jj] = (bf16_t)(p8[jj] * g0);
      a1[jj] = (bf16_t)(p8[jj] * g1);
    }
    acc = __builtin_amdgcn_mfma_f32_16x16x32_bf16(a0, bv0, acc, 0, 0, 0);
    acc = __builtin_amdgcn_mfma_f32_16x16x32_bf16(a1, bv1, acc, 0, 0, 0);
  }

  // ---- R11 epilogue: contention-free coalesced partial store (1 KB/wave).
  // C/D frag: col(u) = lm, row(b within 16) = q*4 + r. Store the raw f32x4
  // per lane; reduce_k undoes the (lane,r) permutation.
  f32x4* pdst = (f32x4*)(part +
      ((((size_t)ns * 16 + btile) * 4 + wave) * 64 + lane) * 4);
  *pdst = acc;
}

// ---------------------------------------------------------------------------
// reduce_k: out[b][u] = sum_ns part[ns][btile][wave][lane=q*16+lm][r]
//   with b = btile*64 + wave*16 + q*4 + r, u = lm.
//   64 blocks x 256 threads; thread t reads the 64 ns slices at byte-identical
//   intra-slice offset t (fully coalesced 1-KB wave reads, 64 independent
//   loads in flight), then writes one out element (coalesced per wave).
// ---------------------------------------------------------------------------
__global__ __launch_bounds__(256) void reduce_k(
    const float* __restrict__ part, float* __restrict__ out) {
  const int t = threadIdx.x;
  const int btile = blockIdx.x >> 2, wave = blockIdx.x & 3;
  const float* p = part + ((size_t)btile * 4 + wave) * 256 + t;
  float s = 0.f;
#pragma unroll
  for (int ns = 0; ns < NSPLIT; ++ns)
    s += p[(size_t)ns * (16 * 4 * 256)];
  const int lane_p = t >> 2, r = t & 3;            // store was (lane)*4 + r
  const int q = lane_p >> 4, lm = lane_p & 15;
  out[(btile * 64 + wave * 16 + q * 4 + r) * U_SZ + lm] = s;
}

// ---------------------------------------------------------------------------
extern "C" void kernel_launch(void* const* d_in, const int* in_sizes, int n_in,
                              void* d_out, int out_size, void* d_ws, size_t ws_size,
                              hipStream_t stream) {
  const float* x    = (const float*)d_in[0];
  const float* fsl  = (const float*)d_in[1];
  const float* th   = (const float*)d_in[2];
  const float* lt   = (const float*)d_in[3];
  const float* resp = (const float*)d_in[4];
  float* out = (float*)d_out;

  char* w = (char*)d_ws;
  bf16_t* selF  = (bf16_t*)(w);                 // 1572864 B  packed sel
  bf16_t* xbF   = (bf16_t*)(w + 1572864);       //  524288 B  packed x
  bf16_t* respF = (bf16_t*)(w + 2097152);       // 1048576 B  packed resp
  float2* sb    = (float2*)(w + 3145728);       //   24576 B  (scale, bias)
  float*  part  = (float*)(w + 3170304);        // 4194304 B  partials [64][16][4][64][4]

  // 0) pack all MFMA operands + sb
  prep_pack<<<716, 256, 0, stream>>>(fsl, x, resp, th, lt,
                                     selF, xbF, respF, sb);

  // 1) fused GEMM + tree eval -> contention-free partials (1024 blocks)
  fused_k<<<16 * NSPLIT, 256, 0, stream>>>(selF, xbF, sb, respF, part);

  // 2) sum the 64 ns slices into out (overwrites; no pre-zero needed)
  reduce_k<<<64, 256, 0, stream>>>(part, out);
}